// Round 1
// baseline (537.250 us; speedup 1.0000x reference)
//
#include <hip/hip_runtime.h>
#include <hip/hip_bf16.h>

#define N_NODES 10000
#define N_EDGES 320000
#define N_REL   460
#define N_BASES 30
#define DIM     200
#define KZ      6016   // 30*200=6000 padded to multiple of 32
#define NPAD    224    // 200 padded to 7*32
#define KS      224    // self-term K (200) padded to multiple of 32

using short8  = __attribute__((ext_vector_type(8))) short;
using floatx4 = __attribute__((ext_vector_type(4))) float;

__device__ __forceinline__ unsigned short f2bf(float f) {
    union { float f; unsigned u; } v; v.f = f;
    unsigned u = v.u;
    return (unsigned short)((u + 0x7fffu + ((u >> 16) & 1u)) >> 16);
}

// ---------------- sort-by-target (counting sort) ----------------

__global__ void zero_deg_kernel(int* deg) {
    int i = blockIdx.x * blockDim.x + threadIdx.x;
    if (i < N_NODES) deg[i] = 0;
}

__global__ void hist_kernel(const int* tgt, int* deg) {
    int e = blockIdx.x * blockDim.x + threadIdx.x;
    if (e < N_EDGES) atomicAdd(&deg[tgt[e]], 1);
}

__global__ __launch_bounds__(1024) void scan_kernel(const int* deg, int* starts,
                                                    int* cursor, float* dinv) {
    __shared__ int part[1024];
    int tid = threadIdx.x;
    const int PER = (N_NODES + 1023) / 1024;  // 10
    int base = tid * PER;
    int s = 0;
    for (int i = 0; i < PER; ++i) { int idx = base + i; if (idx < N_NODES) s += deg[idx]; }
    part[tid] = s; __syncthreads();
    for (int off = 1; off < 1024; off <<= 1) {
        int v = (tid >= off) ? part[tid - off] : 0;
        __syncthreads();
        part[tid] += v;
        __syncthreads();
    }
    int run = (tid > 0) ? part[tid - 1] : 0;
    for (int i = 0; i < PER; ++i) {
        int idx = base + i;
        if (idx < N_NODES) {
            int d = deg[idx];
            starts[idx] = run; cursor[idx] = run;
            dinv[idx] = 1.0f / (float)(d > 0 ? d : 1);
            run += d;
        }
    }
    if (tid == 1023) starts[N_NODES] = part[1023];
}

__global__ void scatter_kernel(const int* src, const int* tgt, const int* etype,
                               int* cursor, int* ssrc, int* stype) {
    int e = blockIdx.x * blockDim.x + threadIdx.x;
    if (e < N_EDGES) {
        int t = tgt[e];
        int pos = atomicAdd(&cursor[t], 1);
        ssrc[pos]  = src[e];
        stype[pos] = etype[e];
    }
}

// ---------------- bf16 operand prep ----------------

// Bt[n][k] = weight[b][kk][n] with k=b*200+kk  (B^T layout, zero-padded)
__global__ void fill_bt_kernel(const float* weight, unsigned short* Bt) {
    int idx = blockIdx.x * blockDim.x + threadIdx.x;
    if (idx >= NPAD * KZ) return;
    int n = idx / KZ, k = idx - n * KZ;
    float v = 0.f;
    if (n < DIM && k < N_BASES * DIM) {
        int b = k / DIM, kk = k - b * DIM;
        v = weight[(b * DIM + kk) * DIM + n];
    }
    Bt[idx] = f2bf(v);
}

__global__ void fill_xb_kernel(const float* x, unsigned short* Xb) {
    int idx = blockIdx.x * blockDim.x + threadIdx.x;
    if (idx >= N_NODES * KS) return;
    int n = idx / KS, k = idx - n * KS;
    Xb[idx] = f2bf(k < DIM ? x[n * DIM + k] : 0.f);
}

// Wst[n][k] = self_weight[k][n]  (transposed, padded)
__global__ void fill_wst_kernel(const float* sw, unsigned short* Wst) {
    int idx = blockIdx.x * blockDim.x + threadIdx.x;
    if (idx >= NPAD * KS) return;
    int n = idx / KS, k = idx - n * KS;
    Wst[idx] = f2bf((n < DIM && k < DIM) ? sw[k * DIM + n] : 0.f);
}

// ---------------- per-target-node aggregation into Z ----------------
// Z[n][b*200+d] = sum over incoming edges of coeff[type,b] * x[src,d], stored bf16.
// Thread (tb=tid&7, td=tid>>3) owns bases tb*4..tb*4+3 and cols td*7..td*7+6.

__global__ __launch_bounds__(256) void agg_kernel(const float* x, const float* coeff,
                                                  const int* starts, const int* ssrc,
                                                  const int* stype, unsigned short* Z) {
    __shared__ float xs[NPAD];   // 224 (200 valid + zero pad)
    __shared__ float cs[32];     // 30 valid + zero pad
    __shared__ __align__(16) unsigned short zs[KZ];
    int n = blockIdx.x;
    int tid = threadIdx.x;
    int tb = tid & 7;
    int td = tid >> 3;
    float acc[4][7];
#pragma unroll
    for (int i = 0; i < 4; ++i)
#pragma unroll
        for (int j = 0; j < 7; ++j) acc[i][j] = 0.f;

    int e0 = starts[n], e1 = starts[n + 1];
    for (int e = e0; e < e1; ++e) {
        int s = ssrc[e], r = stype[e];
        if (tid < NPAD) {
            xs[tid] = (tid < DIM) ? x[(size_t)s * DIM + tid] : 0.f;
        } else {
            int j = tid - NPAD;
            cs[j] = (j < N_BASES) ? coeff[r * N_BASES + j] : 0.f;
        }
        __syncthreads();
        float xx[7];
#pragma unroll
        for (int j = 0; j < 7; ++j) xx[j] = xs[td * 7 + j];
#pragma unroll
        for (int i = 0; i < 4; ++i) {
            float c = cs[tb * 4 + i];
#pragma unroll
            for (int j = 0; j < 7; ++j) acc[i][j] += c * xx[j];
        }
        __syncthreads();
    }
    if (tid < KZ - N_BASES * DIM) zs[N_BASES * DIM + tid] = 0;  // pad cols 6000..6015
#pragma unroll
    for (int i = 0; i < 4; ++i) {
        int b = tb * 4 + i;
#pragma unroll
        for (int j = 0; j < 7; ++j) {
            int d = td * 7 + j;
            if (b < N_BASES && d < DIM) zs[b * DIM + d] = f2bf(acc[i][j]);
        }
    }
    __syncthreads();
    const uint4* zv  = (const uint4*)zs;
    uint4*       dst = (uint4*)(Z + (size_t)n * KZ);
    for (int idx = tid; idx < (KZ * 2) / 16; idx += 256) dst[idx] = zv[idx];
}

// ---------------- fused GEMM: out = (Z@Wcat)*dinv + Xb@Wself + bias ----------------
// block = 256 (4 waves); wave covers 32 rows x 32 cols via 2x2 of 16x16x32 mfma.
// grid: x = ceil(10000/128) row-blocks, y = 224/32 col-blocks.

__global__ __launch_bounds__(256) void gemm_kernel(const unsigned short* Z,
                                                   const unsigned short* Bt,
                                                   const unsigned short* Xb,
                                                   const unsigned short* Wst,
                                                   const float* dinv, const float* bias,
                                                   float* out) {
    int lane = threadIdx.x & 63;
    int wave = threadIdx.x >> 6;
    int row0 = blockIdx.x * 128 + wave * 32;
    int col0 = blockIdx.y * 32;
    int ln = lane & 15;
    int q  = lane >> 4;

    int r0 = row0 + ln, r1 = r0 + 16;
    int r0c = min(r0, N_NODES - 1);
    int r1c = min(r1, N_NODES - 1);
    int c0 = col0 + ln, c1 = c0 + 16;

    const unsigned short* pa0 = Z + (size_t)r0c * KZ + q * 8;
    const unsigned short* pa1 = Z + (size_t)r1c * KZ + q * 8;
    const unsigned short* pb0 = Bt + (size_t)c0 * KZ + q * 8;
    const unsigned short* pb1 = Bt + (size_t)c1 * KZ + q * 8;

    floatx4 acc00 = {0.f, 0.f, 0.f, 0.f};
    floatx4 acc01 = acc00, acc10 = acc00, acc11 = acc00;

    for (int k = 0; k < KZ; k += 32) {
        short8 a0 = *(const short8*)(pa0 + k);
        short8 a1 = *(const short8*)(pa1 + k);
        short8 b0 = *(const short8*)(pb0 + k);
        short8 b1 = *(const short8*)(pb1 + k);
        acc00 = __builtin_amdgcn_mfma_f32_16x16x32_bf16(a0, b0, acc00, 0, 0, 0);
        acc01 = __builtin_amdgcn_mfma_f32_16x16x32_bf16(a0, b1, acc01, 0, 0, 0);
        acc10 = __builtin_amdgcn_mfma_f32_16x16x32_bf16(a1, b0, acc10, 0, 0, 0);
        acc11 = __builtin_amdgcn_mfma_f32_16x16x32_bf16(a1, b1, acc11, 0, 0, 0);
    }

    // scale message part by 1/deg (C layout: row=(lane>>4)*4+i, col=lane&15)
#pragma unroll
    for (int i = 0; i < 4; ++i) {
        float d0 = dinv[min(row0 + q * 4 + i, N_NODES - 1)];
        float d1 = dinv[min(row0 + 16 + q * 4 + i, N_NODES - 1)];
        acc00[i] *= d0; acc01[i] *= d0;
        acc10[i] *= d1; acc11[i] *= d1;
    }

    // self term: += x @ W_self
    const unsigned short* sa0 = Xb + (size_t)r0c * KS + q * 8;
    const unsigned short* sa1 = Xb + (size_t)r1c * KS + q * 8;
    const unsigned short* sb0 = Wst + (size_t)c0 * KS + q * 8;
    const unsigned short* sb1 = Wst + (size_t)c1 * KS + q * 8;
#pragma unroll
    for (int k = 0; k < KS; k += 32) {
        short8 a0 = *(const short8*)(sa0 + k);
        short8 a1 = *(const short8*)(sa1 + k);
        short8 b0 = *(const short8*)(sb0 + k);
        short8 b1 = *(const short8*)(sb1 + k);
        acc00 = __builtin_amdgcn_mfma_f32_16x16x32_bf16(a0, b0, acc00, 0, 0, 0);
        acc01 = __builtin_amdgcn_mfma_f32_16x16x32_bf16(a0, b1, acc01, 0, 0, 0);
        acc10 = __builtin_amdgcn_mfma_f32_16x16x32_bf16(a1, b0, acc10, 0, 0, 0);
        acc11 = __builtin_amdgcn_mfma_f32_16x16x32_bf16(a1, b1, acc11, 0, 0, 0);
    }

    float bi0 = (c0 < DIM) ? bias[c0] : 0.f;
    float bi1 = (c1 < DIM) ? bias[c1] : 0.f;

#pragma unroll
    for (int i = 0; i < 4; ++i) {
        int rr0 = row0 + q * 4 + i;
        int rr1 = rr0 + 16;
        if (rr0 < N_NODES) {
            if (c0 < DIM) out[(size_t)rr0 * DIM + c0] = acc00[i] + bi0;
            if (c1 < DIM) out[(size_t)rr0 * DIM + c1] = acc01[i] + bi1;
        }
        if (rr1 < N_NODES) {
            if (c0 < DIM) out[(size_t)rr1 * DIM + c0] = acc10[i] + bi0;
            if (c1 < DIM) out[(size_t)rr1 * DIM + c1] = acc11[i] + bi1;
        }
    }
}

// ---------------- launch ----------------

extern "C" void kernel_launch(void* const* d_in, const int* in_sizes, int n_in,
                              void* d_out, int out_size, void* d_ws, size_t ws_size,
                              hipStream_t stream) {
    const float* x      = (const float*)d_in[0];
    const float* weight = (const float*)d_in[1];
    const float* coeff  = (const float*)d_in[2];
    const float* selfw  = (const float*)d_in[3];
    const float* bias   = (const float*)d_in[4];
    const int*   eidx   = (const int*)d_in[5];
    const int*   etype  = (const int*)d_in[6];
    const int* src = eidx;
    const int* tgt = eidx + N_EDGES;
    float* out = (float*)d_out;

    char* ws = (char*)d_ws;
    size_t off = 0;
    auto carve = [&](size_t bytes) {
        char* p = ws + off;
        off += (bytes + 255) & ~(size_t)255;
        return p;
    };
    unsigned short* Z    = (unsigned short*)carve((size_t)N_NODES * KZ * 2);
    unsigned short* Bt   = (unsigned short*)carve((size_t)NPAD * KZ * 2);
    unsigned short* Xb   = (unsigned short*)carve((size_t)N_NODES * KS * 2);
    unsigned short* Wst  = (unsigned short*)carve((size_t)NPAD * KS * 2);
    int*   deg    = (int*)carve((size_t)N_NODES * 4);
    int*   starts = (int*)carve((size_t)(N_NODES + 1) * 4);
    int*   cursor = (int*)carve((size_t)N_NODES * 4);
    float* dinv   = (float*)carve((size_t)N_NODES * 4);
    int*   ssrc   = (int*)carve((size_t)N_EDGES * 4);
    int*   stype  = (int*)carve((size_t)N_EDGES * 4);

    zero_deg_kernel<<<(N_NODES + 255) / 256, 256, 0, stream>>>(deg);
    hist_kernel<<<(N_EDGES + 255) / 256, 256, 0, stream>>>(tgt, deg);
    scan_kernel<<<1, 1024, 0, stream>>>(deg, starts, cursor, dinv);
    scatter_kernel<<<(N_EDGES + 255) / 256, 256, 0, stream>>>(src, tgt, etype, cursor, ssrc, stype);

    fill_bt_kernel<<<(NPAD * KZ + 255) / 256, 256, 0, stream>>>(weight, Bt);
    fill_xb_kernel<<<(N_NODES * KS + 255) / 256, 256, 0, stream>>>(x, Xb);
    fill_wst_kernel<<<(NPAD * KS + 255) / 256, 256, 0, stream>>>(selfw, Wst);

    agg_kernel<<<N_NODES, 256, 0, stream>>>(x, coeff, starts, ssrc, stype, Z);

    dim3 grid((N_NODES + 127) / 128, NPAD / 32);
    gemm_kernel<<<grid, 256, 0, stream>>>(Z, Bt, Xb, Wst, dinv, bias, out);
}